// Round 4
// baseline (485.591 us; speedup 1.0000x reference)
//
#include <hip/hip_runtime.h>
#include <hip/hip_bf16.h>
#include <stdint.h>

#define NN 8192
#define KF 512          // IN_F == OUT_F
#define ALPHA 0.2f
#define NTT 64          // j-tiles per k_attn block (64 j each, half of 8192)

typedef __bf16 bf16;
typedef __bf16 bf16x4 __attribute__((ext_vector_type(4)));
typedef __bf16 bf16x8 __attribute__((ext_vector_type(8)));
typedef float  f32x4  __attribute__((ext_vector_type(4)));
typedef float  f32x16 __attribute__((ext_vector_type(16)));

// ---- workspace layout (bytes) ----
static constexpr size_t OFF_HQ  = 0;                            // bf16 hQ interleaved h, 8 MB
static constexpr size_t OFF_XB  = (size_t)8 << 20;              // bf16 [8192][512] = 8 MB
static constexpr size_t OFF_WB  = (size_t)16 << 20;             // bf16 [512][512]  = 512 KB
static constexpr size_t OFF_SRC = OFF_WB + ((size_t)512 << 10); // f32 [8192]
static constexpr size_t OFF_DST = OFF_SRC + (size_t)NN * 4;     // f32 [8192]
static constexpr size_t OFF_PRT = (size_t)17 << 20;             // f32 [2][8192][512] = 32 MB
static constexpr size_t OFF_PDN = OFF_PRT + ((size_t)32 << 20); // f32 [2][8192]

// hQ layout: element (i, c) lives at ((i>>6)*8 + ((i>>3)&7))*4096 + c*8 + (i&7).
// => for fixed c, 8 consecutive i are 16B-contiguous: a 32x32x16 MFMA B-fragment
//    is ONE coalesced 16B load per lane (lanes = consecutive c). [refcheck-proven]

// ---------------- kernel 0: f32 -> bf16 conversion of x and W ----------------
__global__ void k_cvt(const float* __restrict__ x, const float* __restrict__ W,
                      bf16* __restrict__ xb, bf16* __restrict__ wb) {
    const int XQ = (NN * KF) / 4;
    const int TQ = XQ + (KF * KF) / 4;
    for (int i = blockIdx.x * blockDim.x + threadIdx.x; i < TQ;
         i += gridDim.x * blockDim.x) {
        const float4* s;
        bf16* d;
        int o;
        if (i < XQ) { s = (const float4*)x; d = xb; o = i; }
        else        { s = (const float4*)W; d = wb; o = i - XQ; }
        float4 v = s[o];
        bf16x4 b;
        b[0] = (bf16)v.x; b[1] = (bf16)v.y; b[2] = (bf16)v.z; b[3] = (bf16)v.w;
        *(bf16x4*)(d + (size_t)o * 4) = b;
    }
}

// ---------------- kernel 1: h = x @ W^T, emit hQ + src/dst (atomic partial) ----
// [v2, unchanged — refcheck-proven]
__global__ __launch_bounds__(256) void k_gemm(
    const bf16* __restrict__ xb, const bf16* __restrict__ wb,
    bf16* __restrict__ hQ, float* __restrict__ srcv, float* __restrict__ dstv,
    const float* __restrict__ a1, const float* __restrict__ a2) {
    const int tid = threadIdx.x;
    const int wv = tid >> 6;
    const int l = tid & 63;
    const int task = blockIdx.x * 4 + wv;       // 0..4095
    const int rg = task >> 3, cc = task & 7;
    const int i0 = rg * 16, c0 = cc * 64;
    const int lr16 = l & 15, lk = l >> 4;

    f32x4 acc0 = {0.f,0.f,0.f,0.f}, acc1 = acc0, acc2 = acc0, acc3 = acc0;

    const bf16* ap  = xb + (size_t)(i0 + lr16) * KF + lk * 8;
    const bf16* bp0 = wb + (size_t)(c0 +  0 + lr16) * KF + lk * 8;
    const bf16* bp1 = wb + (size_t)(c0 + 16 + lr16) * KF + lk * 8;
    const bf16* bp2 = wb + (size_t)(c0 + 32 + lr16) * KF + lk * 8;
    const bf16* bp3 = wb + (size_t)(c0 + 48 + lr16) * KF + lk * 8;

#pragma unroll 4
    for (int k = 0; k < 16; ++k) {
        bf16x8 a  = *(const bf16x8*)(ap  + k * 32);
        bf16x8 b0 = *(const bf16x8*)(bp0 + k * 32);
        bf16x8 b1 = *(const bf16x8*)(bp1 + k * 32);
        bf16x8 b2 = *(const bf16x8*)(bp2 + k * 32);
        bf16x8 b3 = *(const bf16x8*)(bp3 + k * 32);
        acc0 = __builtin_amdgcn_mfma_f32_16x16x32_bf16(a, b0, acc0, 0, 0, 0);
        acc1 = __builtin_amdgcn_mfma_f32_16x16x32_bf16(a, b1, acc1, 0, 0, 0);
        acc2 = __builtin_amdgcn_mfma_f32_16x16x32_bf16(a, b2, acc2, 0, 0, 0);
        acc3 = __builtin_amdgcn_mfma_f32_16x16x32_bf16(a, b3, acc3, 0, 0, 0);
    }

    const int ib = i0 + lk * 4;
    const int jt = ib >> 6, kq = (ib >> 3) & 7, jr0 = ib & 7;
    float sr[4] = {0.f,0.f,0.f,0.f}, dr[4] = {0.f,0.f,0.f,0.f};
#pragma unroll
    for (int ct = 0; ct < 4; ++ct) {
        const f32x4 av = (ct == 0) ? acc0 : (ct == 1) ? acc1 : (ct == 2) ? acc2 : acc3;
        const int c = c0 + ct * 16 + lr16;
        const float A1 = a1[c], A2 = a2[c];
        bf16x4 hb;
#pragma unroll
        for (int r = 0; r < 4; ++r) {
            float h = av[r];
            sr[r] += h * A1;
            dr[r] += h * A2;
            hb[r] = (bf16)h;
        }
        *(bf16x4*)(hQ + ((size_t)(jt * 8 + kq) * 512 + c) * 8 + jr0) = hb;
    }
#pragma unroll
    for (int r = 0; r < 4; ++r) {
        float s = sr[r], d = dr[r];
        s += __shfl_xor(s, 1, 64); d += __shfl_xor(d, 1, 64);
        s += __shfl_xor(s, 2, 64); d += __shfl_xor(d, 2, 64);
        s += __shfl_xor(s, 4, 64); d += __shfl_xor(d, 4, 64);
        s += __shfl_xor(s, 8, 64); d += __shfl_xor(d, 8, 64);
        if (lr16 == 0) {
            atomicAdd(srcv + ib + r, s);
            atomicAdd(dstv + ib + r, d);
        }
    }
}

// ---------------- kernel 2: fused masked-softmax @ h ----------------
// v4: 1024-thread blocks (16 waves = 4/SIMD — TLP was the v3 bottleneck:
// occupancy 22% grid-capped). Wave owns 32 cols (acc = 2x f32x16). Depth-2
// prefetch of adj/dst/hQ via A/B register banks + unroll-2 (no rotation copy
// => no early forced vmcnt wait). Single barrier/tile, double-buffered p-tile.
__global__ __launch_bounds__(1024) void k_attn(
    const int* __restrict__ adj, const bf16* __restrict__ hQ,
    const float* __restrict__ srcv, const float* __restrict__ dstv,
    float* __restrict__ part, float* __restrict__ pden) {
    __shared__ bf16 pl[2][64][72];   // double-buffered p-tile, bank-clean stride

    const int tid = threadIdx.x;
    const int l = tid & 63;
    const int wv = tid >> 6;             // 0..15
    const int bid = blockIdx.x;
    const int xg = bid & 7, qg = bid >> 3;
    const int js = xg >> 2;              // XCDs 0-3 -> js0, 4-7 -> js1 (hQ half L2-fit)
    const int rt = qg * 4 + (xg & 3);    // 0..127
    const int i0 = rt * 64;
    const int jbase = js * 4096;

    const int pr = tid >> 4;             // p-row 0..63
    const int pj = (tid & 15) * 4;       // p-col offset (4 values/thread)
    const float si = srcv[i0 + pr];

    const int lhi = l >> 5;
    const int l31 = l & 31;
    const int cA = wv * 32 + l31;        // wave owns cols wv*32..+31

    const int*   adjp = adj  + (size_t)(i0 + pr) * NN + jbase + pj;
    const float* dstp = dstv + jbase + pj;
    const bf16*  hqb  = hQ + (size_t)cA * 8;
    const size_t tq0  = (size_t)js * 512;

    f32x16 acc0 = {0.f}, acc1 = {0.f};
    float dacc = 0.f;

    // prologue: tiles 0 (A bank) and 1 (B bank)
    int4   ajA = *(const int4*)(adjp);
    float4 dsA = *(const float4*)(dstp);
    int4   ajB = *(const int4*)(adjp + 64);
    float4 dsB = *(const float4*)(dstp + 64);
    bf16x8 bfA[4], bfB[4];
#pragma unroll
    for (int k = 0; k < 4; ++k) {
        bfA[k] = *(const bf16x8*)(hqb + (tq0 + k * 2 + lhi) * 4096);
        bfB[k] = *(const bf16x8*)(hqb + (tq0 + 8 + k * 2 + lhi) * 4096);
    }

    // phase: consume bank X for tile t, refill X for tile t+2 (clamped)
#define PHASE(T, AJ, DS, BF)                                                     \
    {                                                                            \
        const int t_ = (T);                                                      \
        float w0, w1, w2, w3, e;                                                 \
        e = si + DS.x; e = fmaxf(e, ALPHA * e); w0 = AJ.x ? __expf(e) : 0.f;     \
        e = si + DS.y; e = fmaxf(e, ALPHA * e); w1 = AJ.y ? __expf(e) : 0.f;     \
        e = si + DS.z; e = fmaxf(e, ALPHA * e); w2 = AJ.z ? __expf(e) : 0.f;     \
        e = si + DS.w; e = fmaxf(e, ALPHA * e); w3 = AJ.w ? __expf(e) : 0.f;     \
        bf16x4 pb;                                                               \
        pb[0] = (bf16)w0; pb[1] = (bf16)w1; pb[2] = (bf16)w2; pb[3] = (bf16)w3;  \
        *(bf16x4*)(&pl[t_ & 1][pr][pj]) = pb;                                    \
        dacc += (w0 + w1) + (w2 + w3);                                           \
        const int tp_ = (t_ + 2 < NTT) ? t_ + 2 : t_;   /* clamped, always valid */ \
        AJ = *(const int4*)(adjp + tp_ * 64);                                    \
        DS = *(const float4*)(dstp + tp_ * 64);                                  \
        asm volatile("s_waitcnt lgkmcnt(0)" ::: "memory");  /* drain ds_write */ \
        __builtin_amdgcn_s_barrier();                                            \
        const bf16* plc = &pl[t_ & 1][0][0];                                     \
        _Pragma("unroll")                                                        \
        for (int k = 0; k < 4; ++k) {                                            \
            const int ko = k * 16 + lhi * 8;                                     \
            bf16x8 a0  = *(const bf16x8*)(plc + l31 * 72 + ko);                  \
            bf16x8 a1f = *(const bf16x8*)(plc + (32 + l31) * 72 + ko);           \
            acc0 = __builtin_amdgcn_mfma_f32_32x32x16_bf16(a0,  BF[k], acc0, 0, 0, 0); \
            acc1 = __builtin_amdgcn_mfma_f32_32x32x16_bf16(a1f, BF[k], acc1, 0, 0, 0); \
        }                                                                        \
        const size_t tqp_ = tq0 + (size_t)tp_ * 8;                               \
        _Pragma("unroll")                                                        \
        for (int k = 0; k < 4; ++k)                                              \
            BF[k] = *(const bf16x8*)(hqb + (tqp_ + k * 2 + lhi) * 4096);         \
    }

#pragma unroll 1
    for (int tt = 0; tt < NTT / 2; ++tt) {
        PHASE(2 * tt,     ajA, dsA, bfA)
        PHASE(2 * tt + 1, ajB, dsB, bfB)
    }
#undef PHASE

    // --- epilogue: partial numerators + one-shot denominator reduce ---
    float* pp = part + (size_t)js * NN * KF;
#pragma unroll
    for (int g = 0; g < 16; ++g) {
        const int row = (g & 3) + 8 * (g >> 2) + 4 * lhi;
        pp[(size_t)(i0 + row) * KF + cA]      = acc0[g];
        pp[(size_t)(i0 + 32 + row) * KF + cA] = acc1[g];
    }
    dacc += __shfl_xor(dacc, 1, 64);
    dacc += __shfl_xor(dacc, 2, 64);
    dacc += __shfl_xor(dacc, 4, 64);
    dacc += __shfl_xor(dacc, 8, 64);
    if ((tid & 15) == 0) pden[(size_t)js * NN + i0 + pr] = dacc;
}

// ---------------- kernel 3: combine j-halves and normalize ----------------
__global__ void k_red(const float* __restrict__ part, const float* __restrict__ pden,
                      float* __restrict__ out) {
    int idx = blockIdx.x * blockDim.x + threadIdx.x;   // one float4, total 1M
    const float4 p0 = *(const float4*)(part + (size_t)idx * 4);
    const float4 p1 = *(const float4*)(part + (size_t)NN * KF + (size_t)idx * 4);
    int i = idx >> 7;
    float inv = 1.f / (pden[i] + pden[NN + i]);
    float4 o;
    o.x = (p0.x + p1.x) * inv;
    o.y = (p0.y + p1.y) * inv;
    o.z = (p0.z + p1.z) * inv;
    o.w = (p0.w + p1.w) * inv;
    *(float4*)(out + (size_t)idx * 4) = o;
}

extern "C" void kernel_launch(void* const* d_in, const int* in_sizes, int n_in,
                              void* d_out, int out_size, void* d_ws, size_t ws_size,
                              hipStream_t stream) {
    (void)in_sizes; (void)n_in; (void)out_size; (void)ws_size;
    const float* x  = (const float*)d_in[0];
    const int* adj  = (const int*)d_in[1];
    const float* W  = (const float*)d_in[2];
    const float* a1 = (const float*)d_in[3];
    const float* a2 = (const float*)d_in[4];
    float* out = (float*)d_out;
    char* ws = (char*)d_ws;

    bf16* hQ  = (bf16*)(ws + OFF_HQ);
    bf16* xb  = (bf16*)(ws + OFF_XB);
    bf16* wb  = (bf16*)(ws + OFF_WB);
    float* sv = (float*)(ws + OFF_SRC);
    float* dv = (float*)(ws + OFF_DST);
    float* part = (float*)(ws + OFF_PRT);
    float* pden = (float*)(ws + OFF_PDN);

    hipMemsetAsync(sv, 0, (size_t)2 * NN * sizeof(float), stream);  // srcv+dstv
    k_cvt<<<2048, 256, 0, stream>>>(x, W, xb, wb);
    k_gemm<<<1024, 256, 0, stream>>>(xb, wb, hQ, sv, dv, a1, a2);
    k_attn<<<256, 1024, 0, stream>>>(adj, hQ, sv, dv, part, pden);
    k_red<<<4096, 256, 0, stream>>>(part, pden, out);
}